// Round 5
// baseline (163.877 us; speedup 1.0000x reference)
//
#include <hip/hip_runtime.h>
#include <hip/hip_bf16.h>
#include <cstdint>
#include <cstddef>

// Problem constants (fixed by setup_inputs)
#define NB 8
#define LQ 5440
#define MROWS (NB * LQ)   // 43520

typedef __attribute__((ext_vector_type(8))) _Float16       f16x8;
typedef __attribute__((ext_vector_type(4))) float          f32x4;
typedef __attribute__((ext_vector_type(8))) unsigned short ushort8_t;

__device__ __forceinline__ unsigned short f2h(float f) {
    _Float16 h = (_Float16)f;           // RNE
    unsigned short u;
    __builtin_memcpy(&u, &h, 2);
    return u;
}
__device__ __forceinline__ float h2f(unsigned short u) {
    _Float16 h;
    __builtin_memcpy(&h, &u, 2);
    return (float)h;                    // fpext -> feeds v_fma_mix_f32
}

// ---------------------------------------------------------------------------
// Prep: convert + transpose the 4 weight matrices to fp16 [N][K] layout.
//   WvT [256][256], WoaT [384][256] (off cols 0..255, attn cols 256..383),
//   WoT [256][256].  229376 elements total -> 896 blocks x 256.
// ---------------------------------------------------------------------------
__global__ __launch_bounds__(256) void prep_weights(
    const float* __restrict__ Wv, const float* __restrict__ Woff,
    const float* __restrict__ Wat, const float* __restrict__ Wo,
    unsigned short* __restrict__ WvT, unsigned short* __restrict__ WoaT,
    unsigned short* __restrict__ WoT)
{
    const int id = blockIdx.x * 256 + threadIdx.x;
    if (id < 65536) {
        const int n = id >> 8, k = id & 255;
        WvT[id] = f2h(Wv[k * 256 + n]);
    } else if (id < 65536 + 98304) {
        const int p = id - 65536;
        const int n = p >> 8, k = p & 255;
        WoaT[p] = (n < 256) ? f2h(Woff[k * 256 + n])
                            : f2h(Wat[k * 128 + (n - 256)]);
    } else {
        const int p = id - (65536 + 98304);
        const int n = p >> 8, k = p & 255;
        WoT[p] = f2h(Wo[k * 256 + n]);
    }
}

// ---------------------------------------------------------------------------
// fp16 MFMA GEMM: C[M x N] = A[M x 256] @ Bt^T + bias
//   A: [M][256] fp32 (A_FP32) or fp16;  Bt: [N][256] fp16 (pre-transposed).
//   Tile 128x128, BK=32, 256 threads = 4 waves (2x2 of 64x64).
//   mfma_f32_16x16x32_f16; A frag: lane -> row (l&15), k (l>>4)*8..+7;
//   B frag: lane -> col (l&15), same k;  C/D: col=l&15, row=(l>>4)*4+reg.
//   LDS rows padded to 40 halves (80B).
//   F16_OUT: pack col-pairs via __shfl_xor(1), even lanes store 2xfp16.
//   Column split >= `split` goes to C1 (gemm23 writes off16 + attn16).
// ---------------------------------------------------------------------------
#define LDT 40

template<bool A_FP32, bool F16_OUT>
__global__ __launch_bounds__(256) void gemm_mfma(
    const void* __restrict__ Ap, const unsigned short* __restrict__ Bt,
    const float* __restrict__ bias0, const float* __restrict__ bias1,
    void* __restrict__ C0, void* __restrict__ C1,
    int cs0, int cs1, int split)
{
    __shared__ unsigned short As[128 * LDT];
    __shared__ unsigned short Bs[128 * LDT];

    const int bm = blockIdx.y * 128;
    const int bn = blockIdx.x * 128;
    const int t    = threadIdx.x;
    const int lane = t & 63;
    const int wid  = t >> 6;
    const int wm   = (wid >> 1) * 64;
    const int wn   = (wid & 1) * 64;
    const int c    = lane & 15;
    const int qq   = lane >> 4;

    const int tr = t >> 1;            // staging row 0..127
    const int kh = (t & 1) * 16;      // staging k-half 0/16

    f32x4 acc[4][4];
#pragma unroll
    for (int i = 0; i < 4; ++i)
#pragma unroll
        for (int j = 0; j < 4; ++j)
            acc[i][j] = (f32x4){0.f, 0.f, 0.f, 0.f};

    for (int k0 = 0; k0 < 256; k0 += 32) {
        // ---- stage A (convert fp32->fp16 if needed) ----
        if (A_FP32) {
            const float4* Af = reinterpret_cast<const float4*>(
                (const float*)Ap + (size_t)(bm + tr) * 256 + k0 + kh);
            const float4 a0 = Af[0], a1 = Af[1], a2 = Af[2], a3 = Af[3];
            ushort8_t u0, u1;
            u0[0]=f2h(a0.x); u0[1]=f2h(a0.y); u0[2]=f2h(a0.z); u0[3]=f2h(a0.w);
            u0[4]=f2h(a1.x); u0[5]=f2h(a1.y); u0[6]=f2h(a1.z); u0[7]=f2h(a1.w);
            u1[0]=f2h(a2.x); u1[1]=f2h(a2.y); u1[2]=f2h(a2.z); u1[3]=f2h(a2.w);
            u1[4]=f2h(a3.x); u1[5]=f2h(a3.y); u1[6]=f2h(a3.z); u1[7]=f2h(a3.w);
            *reinterpret_cast<ushort8_t*>(&As[tr * LDT + kh])     = u0;
            *reinterpret_cast<ushort8_t*>(&As[tr * LDT + kh + 8]) = u1;
        } else {
            const ushort8_t* Ab = reinterpret_cast<const ushort8_t*>(
                (const unsigned short*)Ap + (size_t)(bm + tr) * 256 + k0 + kh);
            *reinterpret_cast<ushort8_t*>(&As[tr * LDT + kh])     = Ab[0];
            *reinterpret_cast<ushort8_t*>(&As[tr * LDT + kh + 8]) = Ab[1];
        }
        // ---- stage B ----
        {
            const ushort8_t* Bb = reinterpret_cast<const ushort8_t*>(
                Bt + (size_t)(bn + tr) * 256 + k0 + kh);
            *reinterpret_cast<ushort8_t*>(&Bs[tr * LDT + kh])     = Bb[0];
            *reinterpret_cast<ushort8_t*>(&Bs[tr * LDT + kh + 8]) = Bb[1];
        }
        __syncthreads();

        f16x8 af[4], bfr[4];
#pragma unroll
        for (int i = 0; i < 4; ++i)
            af[i] = *reinterpret_cast<const f16x8*>(
                &As[(wm + i * 16 + c) * LDT + qq * 8]);
#pragma unroll
        for (int j = 0; j < 4; ++j)
            bfr[j] = *reinterpret_cast<const f16x8*>(
                &Bs[(wn + j * 16 + c) * LDT + qq * 8]);
#pragma unroll
        for (int i = 0; i < 4; ++i)
#pragma unroll
            for (int j = 0; j < 4; ++j)
                acc[i][j] = __builtin_amdgcn_mfma_f32_16x16x32_f16(
                    af[i], bfr[j], acc[i][j], 0, 0, 0);
        __syncthreads();
    }

    // ---- epilogue ----
#pragma unroll
    for (int j = 0; j < 4; ++j) {
        const int col    = bn + wn + j * 16 + c;
        const bool second = col >= split;
        const int ccol   = second ? col - split : col;
        const float bv   = second ? bias1[ccol] : bias0[ccol];
#pragma unroll
        for (int i = 0; i < 4; ++i) {
#pragma unroll
            for (int r = 0; r < 4; ++r) {
                const int row = bm + wm + i * 16 + qq * 4 + r;
                const float v0 = acc[i][j][r] + bv;
                if (F16_OUT) {
                    const float v1 = __shfl_xor(v0, 1);
                    if ((lane & 1) == 0) {
                        const unsigned int packed =
                            (unsigned int)f2h(v0) | ((unsigned int)f2h(v1) << 16);
                        unsigned short* Cb = (unsigned short*)(second ? C1 : C0);
                        const int cs = second ? cs1 : cs0;
                        *reinterpret_cast<unsigned int*>(
                            Cb + (size_t)row * cs + ccol) = packed;
                    }
                } else {
                    float* Cf = (float*)C0;
                    Cf[(size_t)row * cs0 + col] = v0;
                }
            }
        }
    }
}

// ---------------------------------------------------------------------------
// Fused sampling, fp16 in/out, precomputed weights+addresses.
//   4 waves/block, wave = one row. Lane (h = lane>>3, k = lane&7) owns
//   channels h*32 + 4k .. +3  (ushort4 index == lane).
//   Precompute: lane computes its 2 (head,sample) pairs -> 4 corner weights
//   (incl. softmax) + 4 byte offsets into v16 -> padded LDS (stride 17/head).
//   Main loop: per sample j: 2 LDS b128 broadcasts + 4 x 8B gathers from a
//   wave-uniform SGPR base (readfirstlane) + 16 v_fma_mix_f32.
// ---------------------------------------------------------------------------
__global__ __launch_bounds__(256) void sample_kernel(
    const unsigned short* __restrict__ v16,     // [NB][LQ][256] fp16
    const unsigned short* __restrict__ off16,   // [NB][LQ][256] fp16
    const unsigned short* __restrict__ attn16,  // [NB][LQ][128] fp16
    const float* __restrict__ refpts,           // [NB][LQ][4][2] fp32
    unsigned short* __restrict__ pre16)         // [NB][LQ][256] fp16
{
    const int lane = threadIdx.x & 63;
    const int wv   = threadIdx.x >> 6;
    const int row  = blockIdx.x * 4 + wv;
    const int n    = row / LQ;

    __shared__ float4 sW[4][136];
    __shared__ int4   sI[4][136];

    const ushort4 o4 = reinterpret_cast<const ushort4*>(off16)[(size_t)row * 64 + lane];
    const unsigned int lg = reinterpret_cast<const unsigned int*>(attn16)[(size_t)row * 64 + lane];
    const float l0 = h2f((unsigned short)(lg & 0xffff));
    const float l1 = h2f((unsigned short)(lg >> 16));

    const int h   = lane >> 3;
    const int k   = lane & 7;
    const int j0  = 2 * k;
    const int lev = j0 >> 2;
    const float rx = refpts[(size_t)row * 8 + lev * 2 + 0];
    const float ry = refpts[(size_t)row * 8 + lev * 2 + 1];

    // softmax across the head's 16 logits (8 lanes x 2)
    float m = fmaxf(l0, l1);
    m = fmaxf(m, __shfl_xor(m, 1));
    m = fmaxf(m, __shfl_xor(m, 2));
    m = fmaxf(m, __shfl_xor(m, 4));
    const float e0 = __expf(l0 - m);
    const float e1 = __expf(l1 - m);
    float s = e0 + e1;
    s += __shfl_xor(s, 1);
    s += __shfl_xor(s, 2);
    s += __shfl_xor(s, 4);
    const float inv = 1.f / s;

    const int  W     = 64 >> lev;
    const int  start = (lev == 0) ? 0 : (lev == 1) ? 4096 : (lev == 2) ? 5120 : 5376;
    const float rs   = 0.015625f * (float)(1 << lev);

#pragma unroll
    for (int pp = 0; pp < 2; ++pp) {
        const float lx = rx + h2f(pp ? o4.z : o4.x) * rs;
        const float ly = ry + h2f(pp ? o4.w : o4.y) * rs;
        const float wgt = (pp ? e1 : e0) * inv;

        const float x = lx * (float)W - 0.5f;
        const float y = ly * (float)W - 0.5f;
        const float fx = floorf(x), fy = floorf(y);
        const int xi = (int)fx, yi = (int)fy;
        const float wx = x - fx, wy = y - fy;

        const int x0 = min(max(xi, 0), W - 1);
        const int x1 = min(max(xi + 1, 0), W - 1);
        const int y0 = min(max(yi, 0), W - 1);
        const int y1 = min(max(yi + 1, 0), W - 1);
        const float vx0 = (xi >= 0 && xi < W)         ? (1.f - wx) : 0.f;
        const float vx1 = (xi + 1 >= 0 && xi + 1 < W) ? wx         : 0.f;
        const float vy0 = (yi >= 0 && yi < W)         ? (1.f - wy) : 0.f;
        const float vy1 = (yi + 1 >= 0 && yi + 1 < W) ? wy         : 0.f;

        // byte offsets into the image's v16 (incl. head channel base h*32ch*2B)
        const int hb  = h * 64;
        const int b00 = (start + y0 * W + x0) * 512 + hb;
        const int b01 = (start + y0 * W + x1) * 512 + hb;
        const int b10 = (start + y1 * W + x0) * 512 + hb;
        const int b11 = (start + y1 * W + x1) * 512 + hb;

        sW[wv][h * 17 + j0 + pp] = make_float4(wgt * vy0 * vx0, wgt * vy0 * vx1,
                                               wgt * vy1 * vx0, wgt * vy1 * vx1);
        sI[wv][h * 17 + j0 + pp] = make_int4(b00, b01, b10, b11);
    }
    __syncthreads();

    // wave-uniform image base -> SGPR, loads become s[base] + v_offset
    const int nu = __builtin_amdgcn_readfirstlane(n);
    const char* vn = reinterpret_cast<const char*>(v16) + (size_t)nu * (LQ * 512);
    const int koff = k * 8;
    float4 acc = make_float4(0.f, 0.f, 0.f, 0.f);

#pragma unroll
    for (int j = 0; j < 16; ++j) {
        const float4 w = sW[wv][h * 17 + j];
        const int4   I = sI[wv][h * 17 + j];
        const ushort4 p00 = *reinterpret_cast<const ushort4*>(vn + (I.x + koff));
        const ushort4 p01 = *reinterpret_cast<const ushort4*>(vn + (I.y + koff));
        const ushort4 p10 = *reinterpret_cast<const ushort4*>(vn + (I.z + koff));
        const ushort4 p11 = *reinterpret_cast<const ushort4*>(vn + (I.w + koff));
        // h2f -> fpext feeds v_fma_mix_f32 (convert folded into FMA)
        acc.x = fmaf(h2f(p00.x), w.x, acc.x);
        acc.x = fmaf(h2f(p01.x), w.y, acc.x);
        acc.x = fmaf(h2f(p10.x), w.z, acc.x);
        acc.x = fmaf(h2f(p11.x), w.w, acc.x);
        acc.y = fmaf(h2f(p00.y), w.x, acc.y);
        acc.y = fmaf(h2f(p01.y), w.y, acc.y);
        acc.y = fmaf(h2f(p10.y), w.z, acc.y);
        acc.y = fmaf(h2f(p11.y), w.w, acc.y);
        acc.z = fmaf(h2f(p00.z), w.x, acc.z);
        acc.z = fmaf(h2f(p01.z), w.y, acc.z);
        acc.z = fmaf(h2f(p10.z), w.z, acc.z);
        acc.z = fmaf(h2f(p11.z), w.w, acc.z);
        acc.w = fmaf(h2f(p00.w), w.x, acc.w);
        acc.w = fmaf(h2f(p01.w), w.y, acc.w);
        acc.w = fmaf(h2f(p10.w), w.z, acc.w);
        acc.w = fmaf(h2f(p11.w), w.w, acc.w);
    }

    ushort4 st;
    st.x = f2h(acc.x); st.y = f2h(acc.y); st.z = f2h(acc.z); st.w = f2h(acc.w);
    // lane (h,k) owns channels h*32+4k..+3  ->  ushort4 index row*64 + lane
    reinterpret_cast<ushort4*>(pre16)[(size_t)row * 64 + lane] = st;
}

// ---------------------------------------------------------------------------
extern "C" void kernel_launch(void* const* d_in, const int* in_sizes, int n_in,
                              void* d_out, int out_size, void* d_ws, size_t ws_size,
                              hipStream_t stream)
{
    const float* query   = (const float*)d_in[0];
    const float* refpts  = (const float*)d_in[1];
    const float* W_value = (const float*)d_in[4];
    const float* b_value = (const float*)d_in[5];
    const float* W_off   = (const float*)d_in[6];
    const float* b_off   = (const float*)d_in[7];
    const float* W_attn  = (const float*)d_in[8];
    const float* b_attn  = (const float*)d_in[9];
    const float* W_out   = (const float*)d_in[10];
    const float* b_out   = (const float*)d_in[11];
    float* out = (float*)d_out;

    // Workspace (fp16): v16 | off16 | attn16 | pre16 | WvT | WoaT | WoT
    unsigned short* ws_v16   = (unsigned short*)d_ws;
    unsigned short* ws_off16 = ws_v16   + (size_t)MROWS * 256;
    unsigned short* ws_at16  = ws_off16 + (size_t)MROWS * 256;
    unsigned short* ws_pre16 = ws_at16  + (size_t)MROWS * 128;
    unsigned short* ws_wvT   = ws_pre16 + (size_t)MROWS * 256;
    unsigned short* ws_woaT  = ws_wvT   + 65536;
    unsigned short* ws_woT   = ws_woaT  + 98304;

    prep_weights<<<dim3(896), 256, 0, stream>>>(
        W_value, W_off, W_attn, W_out, ws_wvT, ws_woaT, ws_woT);

    // v16 = fp16(query @ W_value + b_value)
    gemm_mfma<true, true><<<dim3(2, 340), 256, 0, stream>>>(
        query, ws_wvT, b_value, b_value, ws_v16, ws_v16, 256, 256, 1 << 30);

    // off16 / attn16 = fp16(v @ [W_off | W_attn] + bias)
    gemm_mfma<false, true><<<dim3(3, 340), 256, 0, stream>>>(
        ws_v16, ws_woaT, b_off, b_attn, ws_off16, ws_at16, 256, 128, 256);

    // fused softmax + bilinear sampling -> pre16
    sample_kernel<<<dim3(MROWS / 4), 256, 0, stream>>>(
        ws_v16, ws_off16, ws_at16, refpts, ws_pre16);

    // out = pre @ W_out + b_out  (fp32)
    gemm_mfma<false, false><<<dim3(2, 340), 256, 0, stream>>>(
        ws_pre16, ws_woT, b_out, b_out, out, out, 256, 256, 1 << 30);
}

// Round 6
// 143.746 us; speedup vs baseline: 1.1400x; 1.1400x over previous
//
#include <hip/hip_runtime.h>
#include <hip/hip_bf16.h>
#include <cstdint>
#include <cstddef>

// Problem constants (fixed by setup_inputs)
#define NB 8
#define LQ 5440
#define MROWS (NB * LQ)   // 43520

typedef __attribute__((ext_vector_type(8))) _Float16       f16x8;
typedef __attribute__((ext_vector_type(4))) float          f32x4;
typedef __attribute__((ext_vector_type(8))) unsigned short ushort8_t;

__device__ __forceinline__ unsigned short f2h(float f) {
    _Float16 h = (_Float16)f;           // RNE
    unsigned short u;
    __builtin_memcpy(&u, &h, 2);
    return u;
}
__device__ __forceinline__ float h2f(unsigned short u) {
    _Float16 h;
    __builtin_memcpy(&h, &u, 2);
    return (float)h;                    // fpext -> feeds v_fma_mix_f32
}

// ---------------------------------------------------------------------------
// Prep: convert + transpose the 4 weight matrices to fp16 [N][K] layout.
// ---------------------------------------------------------------------------
__global__ __launch_bounds__(256) void prep_weights(
    const float* __restrict__ Wv, const float* __restrict__ Woff,
    const float* __restrict__ Wat, const float* __restrict__ Wo,
    unsigned short* __restrict__ WvT, unsigned short* __restrict__ WoaT,
    unsigned short* __restrict__ WoT)
{
    const int id = blockIdx.x * 256 + threadIdx.x;
    if (id < 65536) {
        const int n = id >> 8, k = id & 255;
        WvT[id] = f2h(Wv[k * 256 + n]);
    } else if (id < 65536 + 98304) {
        const int p = id - 65536;
        const int n = p >> 8, k = p & 255;
        WoaT[p] = (n < 256) ? f2h(Woff[k * 256 + n])
                            : f2h(Wat[k * 128 + (n - 256)]);
    } else {
        const int p = id - (65536 + 98304);
        const int n = p >> 8, k = p & 255;
        WoT[p] = f2h(Wo[k * 256 + n]);
    }
}

// ---------------------------------------------------------------------------
// fp16 MFMA GEMM: C[M x N] = A[M x 256] @ Bt^T + bias   (unchanged from r5)
// ---------------------------------------------------------------------------
#define LDT 40

template<bool A_FP32, bool F16_OUT>
__global__ __launch_bounds__(256) void gemm_mfma(
    const void* __restrict__ Ap, const unsigned short* __restrict__ Bt,
    const float* __restrict__ bias0, const float* __restrict__ bias1,
    void* __restrict__ C0, void* __restrict__ C1,
    int cs0, int cs1, int split)
{
    __shared__ unsigned short As[128 * LDT];
    __shared__ unsigned short Bs[128 * LDT];

    const int bm = blockIdx.y * 128;
    const int bn = blockIdx.x * 128;
    const int t    = threadIdx.x;
    const int lane = t & 63;
    const int wid  = t >> 6;
    const int wm   = (wid >> 1) * 64;
    const int wn   = (wid & 1) * 64;
    const int c    = lane & 15;
    const int qq   = lane >> 4;

    const int tr = t >> 1;            // staging row 0..127
    const int kh = (t & 1) * 16;      // staging k-half 0/16

    f32x4 acc[4][4];
#pragma unroll
    for (int i = 0; i < 4; ++i)
#pragma unroll
        for (int j = 0; j < 4; ++j)
            acc[i][j] = (f32x4){0.f, 0.f, 0.f, 0.f};

    for (int k0 = 0; k0 < 256; k0 += 32) {
        if (A_FP32) {
            const float4* Af = reinterpret_cast<const float4*>(
                (const float*)Ap + (size_t)(bm + tr) * 256 + k0 + kh);
            const float4 a0 = Af[0], a1 = Af[1], a2 = Af[2], a3 = Af[3];
            ushort8_t u0, u1;
            u0[0]=f2h(a0.x); u0[1]=f2h(a0.y); u0[2]=f2h(a0.z); u0[3]=f2h(a0.w);
            u0[4]=f2h(a1.x); u0[5]=f2h(a1.y); u0[6]=f2h(a1.z); u0[7]=f2h(a1.w);
            u1[0]=f2h(a2.x); u1[1]=f2h(a2.y); u1[2]=f2h(a2.z); u1[3]=f2h(a2.w);
            u1[4]=f2h(a3.x); u1[5]=f2h(a3.y); u1[6]=f2h(a3.z); u1[7]=f2h(a3.w);
            *reinterpret_cast<ushort8_t*>(&As[tr * LDT + kh])     = u0;
            *reinterpret_cast<ushort8_t*>(&As[tr * LDT + kh + 8]) = u1;
        } else {
            const ushort8_t* Ab = reinterpret_cast<const ushort8_t*>(
                (const unsigned short*)Ap + (size_t)(bm + tr) * 256 + k0 + kh);
            *reinterpret_cast<ushort8_t*>(&As[tr * LDT + kh])     = Ab[0];
            *reinterpret_cast<ushort8_t*>(&As[tr * LDT + kh + 8]) = Ab[1];
        }
        {
            const ushort8_t* Bb = reinterpret_cast<const ushort8_t*>(
                Bt + (size_t)(bn + tr) * 256 + k0 + kh);
            *reinterpret_cast<ushort8_t*>(&Bs[tr * LDT + kh])     = Bb[0];
            *reinterpret_cast<ushort8_t*>(&Bs[tr * LDT + kh + 8]) = Bb[1];
        }
        __syncthreads();

        f16x8 af[4], bfr[4];
#pragma unroll
        for (int i = 0; i < 4; ++i)
            af[i] = *reinterpret_cast<const f16x8*>(
                &As[(wm + i * 16 + c) * LDT + qq * 8]);
#pragma unroll
        for (int j = 0; j < 4; ++j)
            bfr[j] = *reinterpret_cast<const f16x8*>(
                &Bs[(wn + j * 16 + c) * LDT + qq * 8]);
#pragma unroll
        for (int i = 0; i < 4; ++i)
#pragma unroll
            for (int j = 0; j < 4; ++j)
                acc[i][j] = __builtin_amdgcn_mfma_f32_16x16x32_f16(
                    af[i], bfr[j], acc[i][j], 0, 0, 0);
        __syncthreads();
    }

#pragma unroll
    for (int j = 0; j < 4; ++j) {
        const int col    = bn + wn + j * 16 + c;
        const bool second = col >= split;
        const int ccol   = second ? col - split : col;
        const float bv   = second ? bias1[ccol] : bias0[ccol];
#pragma unroll
        for (int i = 0; i < 4; ++i) {
#pragma unroll
            for (int r = 0; r < 4; ++r) {
                const int row = bm + wm + i * 16 + qq * 4 + r;
                const float v0 = acc[i][j][r] + bv;
                if (F16_OUT) {
                    const float v1 = __shfl_xor(v0, 1);
                    if ((lane & 1) == 0) {
                        const unsigned int packed =
                            (unsigned int)f2h(v0) | ((unsigned int)f2h(v1) << 16);
                        unsigned short* Cb = (unsigned short*)(second ? C1 : C0);
                        const int cs = second ? cs1 : cs0;
                        *reinterpret_cast<unsigned int*>(
                            Cb + (size_t)row * cs + ccol) = packed;
                    }
                } else {
                    float* Cf = (float*)C0;
                    Cf[(size_t)row * cs0 + col] = v0;
                }
            }
        }
    }
}

// ---------------------------------------------------------------------------
// Fused sampling, 16B-gather remap + 2-deep pipeline.
//   4 waves/block, wave = one row.
//   Main-loop lane roles: h = lane>>3 (head), cp = (lane>>2)&1 (corner pair:
//   0 -> corners (y0,x0),(y0,x1); 1 -> (y1,x0),(y1,x1)), cg = lane&3
//   (channel group: channels h*32 + cg*8 .. +7).
//   Precompute (lane roles h, k=lane&7 -> samples 2k,2k+1): per (sample,cp)
//   one uint4 {w_a, w_b, addr_a, addr_b} into padded LDS (stride 33/head).
//   Main loop per sample j: 1 ds_read_b128 + 2 global dwordx4 (16B/lane,
//   contiguous 64B per (head,pixel)) + 16 fma_mix; next-j LDS read and loads
//   issued before current FMAs (explicit 2-deep pipeline, all-static idx).
//   Epilogue: __shfl_xor(4) combines cp partials; cp==0 lanes store 16B.
// ---------------------------------------------------------------------------
__global__ __launch_bounds__(256) void sample_kernel(
    const unsigned short* __restrict__ v16,     // [NB][LQ][256] fp16
    const unsigned short* __restrict__ off16,   // [NB][LQ][256] fp16
    const unsigned short* __restrict__ attn16,  // [NB][LQ][128] fp16
    const float* __restrict__ refpts,           // [NB][LQ][4][2] fp32
    unsigned short* __restrict__ pre16)         // [NB][LQ][256] fp16
{
    const int lane = threadIdx.x & 63;
    const int wv   = threadIdx.x >> 6;
    const int row  = blockIdx.x * 4 + wv;
    const int n    = row / LQ;

    __shared__ uint4 swi[4][264];   // [wave][h*33 + j*2 + cp]

    const ushort4 o4 = reinterpret_cast<const ushort4*>(off16)[(size_t)row * 64 + lane];
    const unsigned int lg = reinterpret_cast<const unsigned int*>(attn16)[(size_t)row * 64 + lane];
    const float l0 = h2f((unsigned short)(lg & 0xffff));
    const float l1 = h2f((unsigned short)(lg >> 16));

    const int h   = lane >> 3;
    const int k   = lane & 7;
    const int j0  = 2 * k;
    const int lev = k >> 1;
    const float rx = refpts[(size_t)row * 8 + lev * 2 + 0];
    const float ry = refpts[(size_t)row * 8 + lev * 2 + 1];

    // softmax across the head's 16 logits (8 lanes x 2)
    float m = fmaxf(l0, l1);
    m = fmaxf(m, __shfl_xor(m, 1));
    m = fmaxf(m, __shfl_xor(m, 2));
    m = fmaxf(m, __shfl_xor(m, 4));
    const float e0 = __expf(l0 - m);
    const float e1 = __expf(l1 - m);
    float s = e0 + e1;
    s += __shfl_xor(s, 1);
    s += __shfl_xor(s, 2);
    s += __shfl_xor(s, 4);
    const float inv = 1.f / s;

    const int  W     = 64 >> lev;
    const int  start = (lev == 0) ? 0 : (lev == 1) ? 4096 : (lev == 2) ? 5120 : 5376;
    const float rs   = 0.015625f * (float)(1 << lev);

#pragma unroll
    for (int pp = 0; pp < 2; ++pp) {
        const float lx = rx + h2f(pp ? o4.z : o4.x) * rs;
        const float ly = ry + h2f(pp ? o4.w : o4.y) * rs;
        const float wgt = (pp ? e1 : e0) * inv;

        const float x = lx * (float)W - 0.5f;
        const float y = ly * (float)W - 0.5f;
        const float fx = floorf(x), fy = floorf(y);
        const int xi = (int)fx, yi = (int)fy;
        const float wx = x - fx, wy = y - fy;

        const int x0 = min(max(xi, 0), W - 1);
        const int x1 = min(max(xi + 1, 0), W - 1);
        const int y0 = min(max(yi, 0), W - 1);
        const int y1 = min(max(yi + 1, 0), W - 1);
        const float vx0 = (xi >= 0 && xi < W)         ? (1.f - wx) : 0.f;
        const float vx1 = (xi + 1 >= 0 && xi + 1 < W) ? wx         : 0.f;
        const float vy0 = (yi >= 0 && yi < W)         ? (1.f - wy) : 0.f;
        const float vy1 = (yi + 1 >= 0 && yi + 1 < W) ? wy         : 0.f;

        // byte offsets into image (incl. head base h*32ch*2B = h*64)
        const int hb  = h * 64;
        const unsigned int b00 = (unsigned int)((start + y0 * W + x0) * 512 + hb);
        const unsigned int b01 = (unsigned int)((start + y0 * W + x1) * 512 + hb);
        const unsigned int b10 = (unsigned int)((start + y1 * W + x0) * 512 + hb);
        const unsigned int b11 = (unsigned int)((start + y1 * W + x1) * 512 + hb);

        const int jj = j0 + pp;
        uint4 c0, c1;
        c0.x = __float_as_uint(wgt * vy0 * vx0);  // corner (y0,x0)
        c0.y = __float_as_uint(wgt * vy0 * vx1);  // corner (y0,x1)
        c0.z = b00; c0.w = b01;
        c1.x = __float_as_uint(wgt * vy1 * vx0);  // corner (y1,x0)
        c1.y = __float_as_uint(wgt * vy1 * vx1);  // corner (y1,x1)
        c1.z = b10; c1.w = b11;
        swi[wv][h * 33 + jj * 2 + 0] = c0;
        swi[wv][h * 33 + jj * 2 + 1] = c1;
    }
    __syncthreads();

    // ---- main gather loop ----
    const int cp = (lane >> 2) & 1;
    const int cg = lane & 3;
    const unsigned int koff = cg * 16;

    const int nu = __builtin_amdgcn_readfirstlane(n);
    const char* vn = reinterpret_cast<const char*>(v16) + (size_t)nu * (LQ * 512);
    const uint4* wib = &swi[wv][h * 33 + cp];   // stride 2 per sample j

    float acc[8];
#pragma unroll
    for (int i = 0; i < 8; ++i) acc[i] = 0.f;

    // prologue: wi for j=0,1; loads for j=0
    uint4 wiA = wib[0];
    uint4 wiB = wib[2];
    ushort8_t vaA = *reinterpret_cast<const ushort8_t*>(vn + (wiA.z + koff));
    ushort8_t vbA = *reinterpret_cast<const ushort8_t*>(vn + (wiA.w + koff));

#pragma unroll
    for (int j = 0; j < 16; ++j) {
        ushort8_t vaB, vbB;
        if (j < 15) {
            vaB = *reinterpret_cast<const ushort8_t*>(vn + (wiB.z + koff));
            vbB = *reinterpret_cast<const ushort8_t*>(vn + (wiB.w + koff));
        }
        uint4 wiC;
        if (j < 14) wiC = wib[2 * (j + 2)];

        const float wa = __uint_as_float(wiA.x);
        const float wb = __uint_as_float(wiA.y);
#pragma unroll
        for (int i = 0; i < 8; ++i)
            acc[i] = fmaf(h2f(vaA[i]), wa, acc[i]);
#pragma unroll
        for (int i = 0; i < 8; ++i)
            acc[i] = fmaf(h2f(vbA[i]), wb, acc[i]);

        wiA = wiB; wiB = wiC; vaA = vaB; vbA = vbB;
    }

    // combine corner-pair partials (lane ^ 4 flips cp)
#pragma unroll
    for (int i = 0; i < 8; ++i)
        acc[i] += __shfl_xor(acc[i], 4);

    if (cp == 0) {
        ushort8_t st;
#pragma unroll
        for (int i = 0; i < 8; ++i) st[i] = f2h(acc[i]);
        // channels h*32 + cg*8 .. +7
        *reinterpret_cast<ushort8_t*>(
            pre16 + (size_t)row * 256 + h * 32 + cg * 8) = st;
    }
}

// ---------------------------------------------------------------------------
extern "C" void kernel_launch(void* const* d_in, const int* in_sizes, int n_in,
                              void* d_out, int out_size, void* d_ws, size_t ws_size,
                              hipStream_t stream)
{
    const float* query   = (const float*)d_in[0];
    const float* refpts  = (const float*)d_in[1];
    const float* W_value = (const float*)d_in[4];
    const float* b_value = (const float*)d_in[5];
    const float* W_off   = (const float*)d_in[6];
    const float* b_off   = (const float*)d_in[7];
    const float* W_attn  = (const float*)d_in[8];
    const float* b_attn  = (const float*)d_in[9];
    const float* W_out   = (const float*)d_in[10];
    const float* b_out   = (const float*)d_in[11];
    float* out = (float*)d_out;

    // Workspace (fp16): v16 | off16 | attn16 | pre16 | WvT | WoaT | WoT
    unsigned short* ws_v16   = (unsigned short*)d_ws;
    unsigned short* ws_off16 = ws_v16   + (size_t)MROWS * 256;
    unsigned short* ws_at16  = ws_off16 + (size_t)MROWS * 256;
    unsigned short* ws_pre16 = ws_at16  + (size_t)MROWS * 128;
    unsigned short* ws_wvT   = ws_pre16 + (size_t)MROWS * 256;
    unsigned short* ws_woaT  = ws_wvT   + 65536;
    unsigned short* ws_woT   = ws_woaT  + 98304;

    prep_weights<<<dim3(896), 256, 0, stream>>>(
        W_value, W_off, W_attn, W_out, ws_wvT, ws_woaT, ws_woT);

    gemm_mfma<true, true><<<dim3(2, 340), 256, 0, stream>>>(
        query, ws_wvT, b_value, b_value, ws_v16, ws_v16, 256, 256, 1 << 30);

    gemm_mfma<false, true><<<dim3(3, 340), 256, 0, stream>>>(
        ws_v16, ws_woaT, b_off, b_attn, ws_off16, ws_at16, 256, 128, 256);

    sample_kernel<<<dim3(MROWS / 4), 256, 0, stream>>>(
        ws_v16, ws_off16, ws_at16, refpts, ws_pre16);

    gemm_mfma<false, false><<<dim3(2, 340), 256, 0, stream>>>(
        ws_pre16, ws_woT, b_out, b_out, out, out, 256, 256, 1 << 30);
}